// Round 1
// baseline (326.718 us; speedup 1.0000x reference)
//
#include <hip/hip_runtime.h>

// Problem dims (compile-time, all powers of 2)
#define BB 4
#define TT 128
#define II 32
#define HH 64

// d_out layout in floats (reference return order):
// final_carry (B,H) | out (B,T,H) | J_Wi (B,T,H,I,H) | J_Wh (B,T,H,H,H) | J_b (B,T,H,H) | J_h (B,T,H,B,H)
#define OFF_CARRY 0u
#define OFF_OUT   256u
#define OFF_JWI   33024u        // 256 + 32768
#define OFF_JWH   67141888u     // + 67108864
#define OFF_JB    201359616u    // + 134217728
#define OFF_JH    203456768u    // + 2097152
#define OUT_TOTAL 211845376u    // + 8388608

// ---------------------------------------------------------------------------
// Kernel A: sequential RNN scan. 1 block, 256 threads, thread = (b, j).
// Writes out[b,t,j] = a and final carry. g is recomputed later as 1 - a*a.
// ---------------------------------------------------------------------------
__global__ __launch_bounds__(256) void rnn_scan_kernel(
    const float* __restrict__ carry, const float* __restrict__ x,
    const float* __restrict__ Wi, const float* __restrict__ Wh,
    const float* __restrict__ bias, float* __restrict__ out)
{
    __shared__ float sWi[II * HH];   // 8 KB
    __shared__ float sWh[HH * HH];   // 16 KB
    __shared__ float sx[BB * II];    // x_t for all b
    __shared__ float sh[BB * HH];    // h (carry into current step)

    const int tid = threadIdx.x;
    const int b = tid >> 6;          // [0,4)
    const int j = tid & 63;          // [0,64)

    for (int idx = tid; idx < II * HH; idx += 256) sWi[idx] = Wi[idx];
    for (int idx = tid; idx < HH * HH; idx += 256) sWh[idx] = Wh[idx];

    const float bj = bias[j];
    float a_prev = carry[tid];       // h entering step t (t=0: initial carry)
    float* __restrict__ outp = out + OFF_OUT;

    for (int t = 0; t < TT; ++t) {
        __syncthreads();             // previous step's LDS reads done
        if (tid < BB * II)           // load x[:, t, :] (128 floats)
            sx[tid] = x[(((tid >> 5) * TT) + t) * II + (tid & 31)];
        sh[tid] = a_prev;
        __syncthreads();             // sx, sh visible

        float pre = bj;
#pragma unroll
        for (int i = 0; i < II; ++i)
            pre += sx[b * II + i] * sWi[i * HH + j];
#pragma unroll
        for (int m = 0; m < HH; ++m)
            pre += sh[b * HH + m] * sWh[m * HH + j];

        const float a = tanhf(pre);
        outp[(unsigned)(b * TT + t) * HH + j] = a;
        a_prev = a;
    }
    out[tid] = a_prev;               // final carry
}

// ---------------------------------------------------------------------------
// Kernel B: fill all Jacobian regions with vectorized float4 stores.
// Grid-stride over float4 indices of [OFF_JWI, OUT_TOTAL). All region
// boundaries are 64-float4 aligned, so waves never straddle regions.
// ---------------------------------------------------------------------------
__global__ __launch_bounds__(256) void fill_kernel(
    const float* __restrict__ carry, const float* __restrict__ x,
    const float* __restrict__ Wh, float* __restrict__ out)
{
    const unsigned startv = OFF_JWI >> 2;
    const unsigned endv   = OUT_TOTAL >> 2;
    const float* __restrict__ outh = out + OFF_OUT;   // a[b,t,j]
    const unsigned stride = gridDim.x * blockDim.x;

    for (unsigned v = startv + blockIdx.x * blockDim.x + threadIdx.x;
         v < endv; v += stride) {
        const unsigned f = v << 2;                    // flat float index
        float4 r = make_float4(0.f, 0.f, 0.f, 0.f);

        if (f < OFF_JWH) {
            // J_Wi[b,t,j,i,k] = g[b,t,j] * x[b,t,i] * d(j,k)
            const unsigned rel = f - OFF_JWI;
            const unsigned k0  = rel & 63u;           // 4-aligned
            const unsigned row = rel >> 6;
            const unsigned i   = row & 31u;
            const unsigned r2  = row >> 5;
            const unsigned j   = r2 & 63u;
            const unsigned bt  = r2 >> 6;
            const unsigned d   = j - k0;              // unsigned wrap if j<k0
            if (d < 4u) {
                const float a   = outh[bt * 64u + j];
                const float val = (1.0f - a * a) * x[bt * 32u + i];
                if (d == 0u) r.x = val; else if (d == 1u) r.y = val;
                else if (d == 2u) r.z = val; else r.w = val;
            }
        } else if (f < OFF_JB) {
            // J_Wh[b,t,j,m,k] = g[b,t,j] * h[b,t,m] * d(j,k); h = out shifted
            const unsigned rel = f - OFF_JWH;
            const unsigned k0  = rel & 63u;
            const unsigned row = rel >> 6;
            const unsigned m   = row & 63u;
            const unsigned r2  = row >> 6;
            const unsigned j   = r2 & 63u;
            const unsigned bt  = r2 >> 6;
            const unsigned d   = j - k0;
            if (d < 4u) {
                const unsigned t = bt & 127u;
                const float hv = (t == 0u) ? carry[(bt >> 7) * 64u + m]
                                           : outh[(bt - 1u) * 64u + m];
                const float a   = outh[bt * 64u + j];
                const float val = (1.0f - a * a) * hv;
                if (d == 0u) r.x = val; else if (d == 1u) r.y = val;
                else if (d == 2u) r.z = val; else r.w = val;
            }
        } else if (f < OFF_JH) {
            // J_b[b,t,j,k] = g[b,t,j] * d(j,k)
            const unsigned rel = f - OFF_JB;
            const unsigned k0  = rel & 63u;
            const unsigned row = rel >> 6;
            const unsigned j   = row & 63u;
            const unsigned bt  = row >> 6;
            const unsigned d   = j - k0;
            if (d < 4u) {
                const float a   = outh[bt * 64u + j];
                const float val = 1.0f - a * a;
                if (d == 0u) r.x = val; else if (d == 1u) r.y = val;
                else if (d == 2u) r.z = val; else r.w = val;
            }
        } else {
            // J_h[b,t,j,c,m] = g[b,t,j] * Wh[m,j] * d(b,c)  (dense row in m)
            const unsigned rel = f - OFF_JH;
            const unsigned m0  = rel & 63u;
            const unsigned row = rel >> 6;
            const unsigned c   = row & 3u;
            const unsigned r2  = row >> 2;
            const unsigned j   = r2 & 63u;
            const unsigned bt  = r2 >> 6;
            const unsigned b   = bt >> 7;
            if (c == b) {
                const float a = outh[bt * 64u + j];
                const float g = 1.0f - a * a;
                r.x = g * Wh[(m0 + 0u) * 64u + j];
                r.y = g * Wh[(m0 + 1u) * 64u + j];
                r.z = g * Wh[(m0 + 2u) * 64u + j];
                r.w = g * Wh[(m0 + 3u) * 64u + j];
            }
        }
        reinterpret_cast<float4*>(out)[v] = r;
    }
}

extern "C" void kernel_launch(void* const* d_in, const int* in_sizes, int n_in,
                              void* d_out, int out_size, void* d_ws, size_t ws_size,
                              hipStream_t stream) {
    const float* carry = (const float*)d_in[0];
    const float* x     = (const float*)d_in[1];
    const float* Wi    = (const float*)d_in[2];
    const float* Wh    = (const float*)d_in[3];
    const float* bias  = (const float*)d_in[4];
    float* out = (float*)d_out;

    rnn_scan_kernel<<<1, 256, 0, stream>>>(carry, x, Wi, Wh, bias, out);
    fill_kernel<<<2048, 256, 0, stream>>>(carry, x, Wh, out);
}

// Round 3
// 206.748 us; speedup vs baseline: 1.5803x; 1.5803x over previous
//
#include <hip/hip_runtime.h>
#include <math.h>

// Problem dims: B=4, T=128, I=32, H=64 (all compile-time)
// d_out float layout (reference return order):
// final_carry (4,64) | out (4,128,64) | J_Wi (4,128,64,32,64) | J_Wh (4,128,64,64,64) | J_b (4,128,64,64) | J_h (4,128,64,4,64)
#define OFF_OUT   256u
#define OFF_JWI   33024u
#define OFF_JWH   67141888u
#define OFF_JB    201359616u
#define OFF_JH    203456768u

typedef float f32x4 __attribute__((ext_vector_type(4)));

static __device__ __forceinline__ float tanh_fast(float x) {
    // tanh(x) = 1 - 2/(e^{2x}+1); exact limits at +-inf, ~1e-6 rel error
    float t = __expf(2.0f * x);
    return 1.0f - 2.0f / (t + 1.0f);
}

static __device__ __forceinline__ void nt_store4(f32x4* p, float a, float b,
                                                 float c, float d) {
    f32x4 r = {a, b, c, d};
    __builtin_nontemporal_store(r, p);
}

// ---------------------------------------------------------------------------
// Kernel 1: u[bt,j] = b[j] + sum_i x[bt,i]*Wi[i,j]   (staged into J_b region,
// which the fill kernel overwrites afterwards). 128 blocks x 256 threads.
// ---------------------------------------------------------------------------
__global__ __launch_bounds__(256) void xwi_kernel(
    const float* __restrict__ x, const float* __restrict__ Wi,
    const float* __restrict__ bias, float* __restrict__ u)
{
    const int tid = threadIdx.x;
    const int row = blockIdx.x * 4 + (tid >> 6);   // bt in [0,512)
    const int j = tid & 63;
    const float* xr = x + row * 32;
    float acc = bias[j];
#pragma unroll
    for (int i = 0; i < 32; ++i) acc = fmaf(xr[i], Wi[i * 64 + j], acc);
    u[row * 64 + j] = acc;
}

// ---------------------------------------------------------------------------
// Kernel 2: sequential scan, one block (1 wave) per batch b. Thread = j.
// Wh column j lives in 64 registers; h broadcast via LDS.
// ---------------------------------------------------------------------------
__global__ __launch_bounds__(64) void scan_kernel(
    const float* __restrict__ carry, const float* __restrict__ u,
    const float* __restrict__ Wh, float* __restrict__ out)
{
    const int b = blockIdx.x;
    const int j = threadIdx.x;
    float wcol[64];
#pragma unroll
    for (int m = 0; m < 64; ++m) wcol[m] = Wh[m * 64 + j];

    __shared__ float sh[64];
    sh[j] = carry[b * 64 + j];
    const float* ub = u + b * 128 * 64;
    float* ob = out + OFF_OUT + b * 128 * 64;
    float unext = ub[j];
    float a = 0.0f;
    __syncthreads();

    for (int t = 0; t < 128; ++t) {
        const float pre0 = unext;
        if (t < 127) unext = ub[(t + 1) * 64 + j];   // prefetch next step
        float a0 = 0.f, a1 = 0.f, a2 = 0.f, a3 = 0.f;
#pragma unroll
        for (int m = 0; m < 64; m += 4) {
            a0 = fmaf(sh[m + 0], wcol[m + 0], a0);
            a1 = fmaf(sh[m + 1], wcol[m + 1], a1);
            a2 = fmaf(sh[m + 2], wcol[m + 2], a2);
            a3 = fmaf(sh[m + 3], wcol[m + 3], a3);
        }
        a = tanh_fast(pre0 + (a0 + a1) + (a2 + a3));
        ob[t * 64 + j] = a;
        __syncthreads();
        sh[j] = a;
        __syncthreads();
    }
    out[b * 64 + j] = a;   // final carry
}

// ---------------------------------------------------------------------------
// Kernel 3: fill J_Wi / J_Wh / J_b. Block-contiguous 256 KB chunks, all reads
// LDS-staged once, non-temporal float4 stores.
//   blk [0,1024):    J_Wi  (bt = blk>>1, j-half = blk&1)
//   blk [1024,3072): J_Wh  (idx=blk-1024: bt = idx>>2, j-quarter = idx&3)
//   blk [3072,3104): J_b   (c = blk-3072: rows [c*1024, c*1024+1024))
// ---------------------------------------------------------------------------
__global__ __launch_bounds__(256) void fill_main(
    const float* __restrict__ carry, const float* __restrict__ x,
    float* __restrict__ out)
{
    __shared__ float smem[1024];
    const int tid = threadIdx.x;
    const unsigned blk = blockIdx.x;
    const float* __restrict__ outh = out + OFF_OUT;
    const unsigned rowq = tid >> 4;          // 16-lane group id [0,16)
    const unsigned k0 = (tid & 15u) * 4;     // k offset of this lane's float4

    if (blk < 1024u) {
        const unsigned bt = blk >> 1, jh = blk & 1u;
        if (tid < 32) {
            const float aa = outh[bt * 64 + jh * 32 + tid];
            smem[tid] = 1.0f - aa * aa;          // g[jloc]
            smem[32 + tid] = x[bt * 32 + tid];   // x[i]
        }
        __syncthreads();
        f32x4* dst = reinterpret_cast<f32x4*>(
            out + (size_t)OFF_JWI + (size_t)bt * 131072 + jh * 65536);
        const unsigned jbase = jh * 32;
#pragma unroll 2
        for (int it = 0; it < 64; ++it) {
            const unsigned R = it * 16 + rowq;        // row (jloc,i) in [0,1024)
            const unsigned jloc = R >> 5, i = R & 31u;
            const float val = smem[jloc] * smem[32 + i];
            const unsigned d = (jbase + jloc) - k0;   // wraps if j<k0
            nt_store4(dst + it * 256 + tid,
                      (d == 0u) ? val : 0.f, (d == 1u) ? val : 0.f,
                      (d == 2u) ? val : 0.f, (d == 3u) ? val : 0.f);
        }
    } else if (blk < 3072u) {
        const unsigned idx = blk - 1024u;
        const unsigned bt = idx >> 2, jq = idx & 3u;
        const unsigned t = bt & 127u, bb = bt >> 7;
        if (tid < 16) {
            const float aa = outh[bt * 64 + jq * 16 + tid];
            smem[tid] = 1.0f - aa * aa;              // g[jloc]
        } else if (tid >= 64 && tid < 128) {
            const unsigned m = tid - 64;
            smem[64 + m] = (t == 0u) ? carry[bb * 64 + m]
                                     : outh[(bt - 1u) * 64 + m];  // h entering step t
        }
        __syncthreads();
        f32x4* dst = reinterpret_cast<f32x4*>(
            out + (size_t)OFF_JWH + (size_t)bt * 262144 + jq * 65536);
        const unsigned jbase = jq * 16;
#pragma unroll 2
        for (int it = 0; it < 64; ++it) {
            const unsigned R = it * 16 + rowq;        // row (jloc,m) in [0,1024)
            const unsigned jloc = R >> 6, m = R & 63u;
            const float val = smem[jloc] * smem[64 + m];
            const unsigned d = (jbase + jloc) - k0;
            nt_store4(dst + it * 256 + tid,
                      (d == 0u) ? val : 0.f, (d == 1u) ? val : 0.f,
                      (d == 2u) ? val : 0.f, (d == 3u) ? val : 0.f);
        }
    } else {
        const unsigned c = blk - 3072u;
        for (int p = tid; p < 1024; p += 256) {
            const float aa = outh[c * 1024 + p];      // row index == outh index
            smem[p] = 1.0f - aa * aa;
        }
        __syncthreads();
        f32x4* dst = reinterpret_cast<f32x4*>(
            out + (size_t)OFF_JB + (size_t)c * 65536);
#pragma unroll 2
        for (int it = 0; it < 64; ++it) {
            const unsigned R = it * 16 + rowq;        // local row
            const unsigned j = R & 63u;               // c*1024 is 64-aligned
            const float val = smem[R];
            const unsigned d = j - k0;
            nt_store4(dst + it * 256 + tid,
                      (d == 0u) ? val : 0.f, (d == 1u) ? val : 0.f,
                      (d == 2u) ? val : 0.f, (d == 3u) ? val : 0.f);
        }
    }
}

// ---------------------------------------------------------------------------
// Kernel 4: fill J_h. One block per 4 (b,t) slabs; Wh^T staged in LDS
// (stride 68 floats: 16B-aligned rows, 2-way-max bank aliasing on reads).
// J_h[b,t,j,c,m] = g[b,t,j] * Wh[m,j] * delta(b,c)
// ---------------------------------------------------------------------------
__global__ __launch_bounds__(256) void fill_jh(
    const float* __restrict__ Wh, float* __restrict__ out)
{
    __shared__ float whT[64 * 68];
    __shared__ float sg[256];
    const int tid = threadIdx.x;
    const unsigned q = blockIdx.x;                   // [0,128): 4 slabs each
    const float* __restrict__ outh = out + OFF_OUT;

    for (int p = tid; p < 4096; p += 256) {
        const unsigned m = p >> 6, j = p & 63u;
        whT[j * 68 + m] = Wh[p];
    }
    {
        const unsigned s = tid >> 6, j = tid & 63u;
        const float aa = outh[(q * 4 + s) * 64 + j];
        sg[tid] = 1.0f - aa * aa;
    }
    __syncthreads();

    const unsigned m0 = (tid & 15u) * 4;
    f32x4* dst = reinterpret_cast<f32x4*>(out + (size_t)OFF_JH + (size_t)q * 65536);
#pragma unroll 2
    for (int it = 0; it < 64; ++it) {
        const unsigned R = it * 16 + (tid >> 4);     // row = s*256 + j*4 + c
        const unsigned s = R >> 8;
        const unsigned j = (R >> 2) & 63u;
        const unsigned cc = R & 3u;
        const unsigned bb = (q * 4 + s) >> 7;        // b of this slab
        if (cc == bb) {
            const float g = sg[s * 64 + j];
            const float* wrow = &whT[j * 68 + m0];
            nt_store4(dst + it * 256 + tid,
                      g * wrow[0], g * wrow[1], g * wrow[2], g * wrow[3]);
        } else {
            nt_store4(dst + it * 256 + tid, 0.f, 0.f, 0.f, 0.f);
        }
    }
}

extern "C" void kernel_launch(void* const* d_in, const int* in_sizes, int n_in,
                              void* d_out, int out_size, void* d_ws, size_t ws_size,
                              hipStream_t stream) {
    const float* carry = (const float*)d_in[0];
    const float* x     = (const float*)d_in[1];
    const float* Wi    = (const float*)d_in[2];
    const float* Wh    = (const float*)d_in[3];
    const float* bias  = (const float*)d_in[4];
    float* out = (float*)d_out;
    float* u = out + OFF_JB;   // stage x@Wi+b here; overwritten by fill_main later

    xwi_kernel <<<128, 256, 0, stream>>>(x, Wi, bias, u);
    scan_kernel<<<4, 64, 0, stream>>>(carry, u, Wh, out);
    fill_main  <<<3104, 256, 0, stream>>>(carry, x, out);
    fill_jh    <<<128, 256, 0, stream>>>(Wh, out);
}

// Round 4
// 184.443 us; speedup vs baseline: 1.7714x; 1.1209x over previous
//
#include <hip/hip_runtime.h>
#include <math.h>

// Problem dims: B=4, T=128, I=32, H=64 (compile-time)
// d_out float layout (reference return order):
// final_carry (4,64) | out (4,128,64) | J_Wi (4,128,64,32,64) | J_Wh (4,128,64,64,64)
// | J_b (4,128,64,64) | J_h (4,128,64,4,64)
#define OFF_OUT   256u
#define OFF_JWI   33024u
#define OFF_JWH   67141888u
#define OFF_JB    201359616u
#define OFF_JH    203456768u

typedef float f32x4 __attribute__((ext_vector_type(4)));

static __device__ __forceinline__ float tanh_fast(float x) {
    // tanh(x) = 1 - 2/(e^{2x}+1); exact limits, ~1e-6 rel error
    float t = __expf(2.0f * x);
    return 1.0f - 2.0f / (t + 1.0f);
}

// ---------------------------------------------------------------------------
// Kernel 1: u[bt,j] = b[j] + sum_i x[bt,i]*Wi[i,j]  (staged at start of J_b
// region; kernel3 overwrites it afterwards). 128 blocks x 256 threads.
// ---------------------------------------------------------------------------
__global__ __launch_bounds__(256) void xwi_kernel(
    const float* __restrict__ x, const float* __restrict__ Wi,
    const float* __restrict__ bias, float* __restrict__ u)
{
    const int tid = threadIdx.x;
    const int row = blockIdx.x * 4 + (tid >> 6);   // bt in [0,512)
    const int j = tid & 63;
    const float* xr = x + row * 32;
    float acc = bias[j];
#pragma unroll
    for (int i = 0; i < 32; ++i) acc = fmaf(xr[i], Wi[i * 64 + j], acc);
    u[row * 64 + j] = acc;
}

// ---------------------------------------------------------------------------
// Kernel 2: block 0 = sequential scan (wave w = batch w, barrier-free: each
// wave touches only its own sh slice, same-wave LDS ordering is enough).
// Blocks 1..G-1 = zero-fill of all structurally-zero half-lines:
//   unit < 131072:  J_Wi non-diag 128B half-lines (unit = 8 rows)
//   unit < 393216:  J_Wh non-diag 128B half-lines (unit = 8 rows)
//   else         :  J_h flat memset (unit = 256 floats)
// ---------------------------------------------------------------------------
__global__ __launch_bounds__(256) void scan_zero_kernel(
    const float* __restrict__ carry, const float* __restrict__ u,
    const float* __restrict__ Wh, float* __restrict__ out)
{
    const int tid = threadIdx.x;
    if (blockIdx.x == 0) {
        const int w = tid >> 6, j = tid & 63;
        float wcol[64];
#pragma unroll
        for (int m = 0; m < 64; ++m) wcol[m] = Wh[m * 64 + j];
        __shared__ __align__(16) float sh[256];
        sh[tid] = carry[tid];
        const float* ub = u + w * 8192;
        float* ob = out + OFF_OUT + w * 8192;
        const f32x4* shv = reinterpret_cast<const f32x4*>(sh + w * 64);
        float unext = ub[j];
        float a = 0.0f;
        for (int t = 0; t < 128; ++t) {
            const float pre = unext;
            if (t < 127) unext = ub[(t + 1) * 64 + j];
            float a0 = 0.f, a1 = 0.f, a2 = 0.f, a3 = 0.f;
#pragma unroll
            for (int mm = 0; mm < 16; ++mm) {
                const f32x4 hv = shv[mm];           // lane-uniform 16B read
                a0 = fmaf(hv.x, wcol[mm * 4 + 0], a0);
                a1 = fmaf(hv.y, wcol[mm * 4 + 1], a1);
                a2 = fmaf(hv.z, wcol[mm * 4 + 2], a2);
                a3 = fmaf(hv.w, wcol[mm * 4 + 3], a3);
            }
            a = tanh_fast(pre + (a0 + a1) + (a2 + a3));
            ob[t * 64 + j] = a;
            sh[tid] = a;                             // next iter reads it
        }
        out[tid] = a;                                // final carry
    } else {
        const unsigned NW = (gridDim.x - 1u) * 4u;
        const unsigned l = tid & 63u;
        const f32x4 z = {0.f, 0.f, 0.f, 0.f};
        for (unsigned uu = (blockIdx.x - 1u) * 4u + (tid >> 6);
             uu < 425984u; uu += NW) {
            unsigned addr;
            if (uu < 131072u) {
                const unsigned r0 = uu * 8u;                 // J_Wi row
                const unsigned j = (r0 >> 5) & 63u;          // uniform over 8 rows
                addr = OFF_JWI + r0 * 64u + ((j < 32u) ? 32u : 0u)
                     + (l >> 3) * 64u + (l & 7u) * 4u;
            } else if (uu < 393216u) {
                const unsigned r0 = (uu - 131072u) * 8u;     // J_Wh row
                const unsigned j = (r0 >> 6) & 63u;
                addr = OFF_JWH + r0 * 64u + ((j < 32u) ? 32u : 0u)
                     + (l >> 3) * 64u + (l & 7u) * 4u;
            } else {
                addr = OFF_JH + (uu - 393216u) * 256u + l * 4u;
            }
            __builtin_nontemporal_store(z, reinterpret_cast<f32x4*>(out + addr));
        }
    }
}

// ---------------------------------------------------------------------------
// Kernel 3: data-dependent fill (diag half-lines + dense J_h rows).
//   unit < 131072:  J_Wi diag halves   (unit = 8 rows, 1 f32x4/lane)
//   unit < 393216:  J_Wh diag halves   (unit = 8 rows)
//   unit < 401408:  J_b full rows      (unit = 4 rows of 64 floats)
//   else         :  J_h c==b rows      (unit = 4 (bt,j) rows of 64 floats)
// ---------------------------------------------------------------------------
__global__ __launch_bounds__(256) void diag_fill_kernel(
    const float* __restrict__ carry, const float* __restrict__ x,
    const float* __restrict__ Wh, float* __restrict__ out)
{
    const int tid = threadIdx.x;
    const unsigned NW = gridDim.x * 4u;
    const unsigned l = tid & 63u;
    const float* __restrict__ outh = out + OFF_OUT;

    for (unsigned uu = blockIdx.x * 4u + (tid >> 6); uu < 409600u; uu += NW) {
        unsigned addr;
        f32x4 r = {0.f, 0.f, 0.f, 0.f};
        if (uu < 131072u) {
            const unsigned r0 = uu * 8u;
            const unsigned bt = r0 >> 11;
            const unsigned j = (r0 >> 5) & 63u;
            const float a = outh[bt * 64u + j];          // wave-uniform
            const float g = 1.0f - a * a;
            const unsigned i = (r0 + (l >> 3)) & 31u;
            const float v = g * x[bt * 32u + i];
            const unsigned d = (j & 31u) - (l & 7u) * 4u; // wraps if diag elsewhere
            r.x = (d == 0u) ? v : 0.f; r.y = (d == 1u) ? v : 0.f;
            r.z = (d == 2u) ? v : 0.f; r.w = (d == 3u) ? v : 0.f;
            addr = OFF_JWI + r0 * 64u + ((j < 32u) ? 0u : 32u)
                 + (l >> 3) * 64u + (l & 7u) * 4u;
        } else if (uu < 393216u) {
            const unsigned r0 = (uu - 131072u) * 8u;
            const unsigned bt = r0 >> 12;
            const unsigned j = (r0 >> 6) & 63u;
            const unsigned t = bt & 127u, b = bt >> 7;
            const float a = outh[bt * 64u + j];
            const float g = 1.0f - a * a;
            const unsigned m = (r0 + (l >> 3)) & 63u;
            const float hv = (t == 0u) ? carry[b * 64u + m]
                                       : outh[(bt - 1u) * 64u + m];
            const float v = g * hv;
            const unsigned d = (j & 31u) - (l & 7u) * 4u;
            r.x = (d == 0u) ? v : 0.f; r.y = (d == 1u) ? v : 0.f;
            r.z = (d == 2u) ? v : 0.f; r.w = (d == 3u) ? v : 0.f;
            addr = OFF_JWH + r0 * 64u + ((j < 32u) ? 0u : 32u)
                 + (l >> 3) * 64u + (l & 7u) * 4u;
        } else if (uu < 401408u) {
            const unsigned p = (uu - 393216u) * 4u + (l >> 4);  // row = bt*64+j
            const unsigned j = p & 63u;
            const float a = outh[p];
            const float g = 1.0f - a * a;
            const unsigned d = j - (l & 15u) * 4u;
            r.x = (d == 0u) ? g : 0.f; r.y = (d == 1u) ? g : 0.f;
            r.z = (d == 2u) ? g : 0.f; r.w = (d == 3u) ? g : 0.f;
            addr = OFF_JB + p * 64u + (l & 15u) * 4u;
        } else {
            const unsigned p = (uu - 401408u) * 4u + (l >> 4);  // bt*64+j
            const unsigned bt = p >> 6, j = p & 63u, b = bt >> 7;
            const float a = outh[p];
            const float g = 1.0f - a * a;
            const unsigned k0 = (l & 15u) * 4u;
            r.x = g * Wh[(k0 + 0u) * 64u + j];
            r.y = g * Wh[(k0 + 1u) * 64u + j];
            r.z = g * Wh[(k0 + 2u) * 64u + j];
            r.w = g * Wh[(k0 + 3u) * 64u + j];
            addr = OFF_JH + p * 256u + b * 64u + k0;
        }
        __builtin_nontemporal_store(r, reinterpret_cast<f32x4*>(out + addr));
    }
}

extern "C" void kernel_launch(void* const* d_in, const int* in_sizes, int n_in,
                              void* d_out, int out_size, void* d_ws, size_t ws_size,
                              hipStream_t stream) {
    const float* carry = (const float*)d_in[0];
    const float* x     = (const float*)d_in[1];
    const float* Wi    = (const float*)d_in[2];
    const float* Wh    = (const float*)d_in[3];
    const float* bias  = (const float*)d_in[4];
    float* out = (float*)d_out;
    float* u = out + OFF_JB;   // staging; overwritten by diag_fill_kernel

    xwi_kernel      <<<128, 256, 0, stream>>>(x, Wi, bias, u);
    scan_zero_kernel<<<2048, 256, 0, stream>>>(carry, u, Wh, out);
    diag_fill_kernel<<<2048, 256, 0, stream>>>(carry, x, Wh, out);
}